// Round 16
// baseline (61.379 us; speedup 1.0000x reference)
//
#include <hip/hip_runtime.h>

typedef __attribute__((ext_vector_type(4))) float f32x4;
typedef __attribute__((ext_vector_type(2))) long i64x2;

#define SCALE 262144.0f                 // 2^18 codebook prescale
#define NEG2S -524288.0f                // -2 * SCALE
#define INV_S2 1.4551915228366852e-11f  // 2^-36, exact
#define OFFS35 34359738368.0f           // 2^35 positivity offset (scaled units)

static __device__ __forceinline__ unsigned umin2(unsigned a, unsigned b) { return a < b ? a : b; }

// exact e4m3fn decode (bias 7, 3-bit mantissa, denormals at 2^-9)
static __device__ __forceinline__ float dec_e4m3(unsigned b) {
  int e = (b >> 3) & 15, m = b & 7;
  float v = e ? ldexpf((float)(8 + m), e - 10) : ldexpf((float)m, -9);
  return (b & 0x80) ? -v : v;
}

// ---------------- Kernel 1: prep ----------------
// codebook fp32 -> (x SCALE) -> fp8 e4m3, PERMUTED: k = ks*32+hi*8+j stored at
// byte hi*64 + ks*8 + j (B-fragment order, ds_read_b128 covers 2 k-steps).
// norms[code] = 2^35 + sum(dec^2)  (offset makes all scores positive).
__global__ void vq_prep(const float* __restrict__ cb,
                        float* __restrict__ norms,
                        unsigned char* __restrict__ cbh,
                        float* __restrict__ loss_out) {
  if (blockIdx.x == 0 && threadIdx.x == 0) *loss_out = 0.0f;
  const int lane = threadIdx.x & 63;
  const int code = (blockIdx.x * blockDim.x + threadIdx.x) >> 6;  // one wave per code
  const f32x4 v = ((const f32x4*)(cb + (long)code * 256))[lane];  // k = 4*lane .. +3
  unsigned w = __builtin_amdgcn_cvt_pk_fp8_f32(v[0] * SCALE, v[1] * SCALE, 0, false);
  w = __builtin_amdgcn_cvt_pk_fp8_f32(v[2] * SCALE, v[3] * SCALE, w, true);
  float n = 0.f;
#pragma unroll
  for (int j = 0; j < 4; ++j) {
    float d = dec_e4m3((w >> (8 * j)) & 0xFFu);
    n = __builtin_fmaf(d, d, n);
  }
  // k0 = 4*lane: ks = lane>>3, hi = (lane>>1)&3, j0 = (lane&1)*4
  const int newpos = ((lane >> 1) & 3) * 64 + (lane >> 3) * 8 + (lane & 1) * 4;
  *(unsigned*)(cbh + (long)code * 256 + newpos) = w;
#pragma unroll
  for (int m = 1; m < 64; m <<= 1) n += __shfl_xor(n, m);
  if (lane == 0) norms[code] = n + OFFS35;
}

// ---------------- Kernel 2: main ----------------
// 8 waves = 4 row-groups (32 rows, M_w=32) x 2 code-halves (512 codes each).
#define BM 128    // rows per block
#define DD 256    // embedding dim
#define NTHR 512  // 8 waves
#define NSUB 16   // 1024 codes / 64 per subtile

__global__ __launch_bounds__(NTHR, 4)
void vq_main(const float* __restrict__ X,
             const float* __restrict__ CB,
             const float* __restrict__ norms_g,
             const unsigned char* __restrict__ cbh,
             float* __restrict__ out,
             float* __restrict__ loss_out,
             float lscale) {
  // E double buffer: 2 x (64 codes x 256B fp8) = 32 KiB
  __shared__ __attribute__((aligned(16))) unsigned char Eb[2 * 16384];
  __shared__ __attribute__((aligned(16))) float nrmLds[1024];  // 4 KiB fp32
  __shared__ unsigned keys[BM];
  __shared__ float wsumX[8];
  __shared__ float wsumS[8];

  const int t = threadIdx.x;
  const int lane = t & 63;
  const int wave = t >> 6;   // 0..7
  const int wr = wave >> 1;  // 0..3 : row-group (32 rows)
  const int wc = wave & 1;   // 0..1 : code half (512 codes)
  const int lo16 = lane & 15;
  const int hi = lane >> 4;
  const long rowBase = (long)blockIdx.x * BM;

  // ---- staging: subtile = 16 KiB; 8 waves x 2 chunks x (64 lanes x 16B).
  // LDS dest linear; global SOURCE pre-swizzled with involution o ^= ((o>>8)&7)<<4.
  const char* cbB = (const char*)cbh;
  char* ebBase = (char*)Eb;
#define STAGE_E(ST, BUF)                                                                      \
  {                                                                                           \
    _Pragma("unroll") for (int c = 0; c < 2; ++c) {                                           \
      unsigned o = (unsigned)(wave * 2048 + c * 1024 + lane * 16);                            \
      unsigned src = o ^ ((((o >> 8) & 7u)) << 4);                                            \
      __builtin_amdgcn_global_load_lds(                                                       \
          (const __attribute__((address_space(1))) void*)(cbB + (unsigned)(ST)*16384u + src), \
          (__attribute__((address_space(3))) void*)(ebBase + (unsigned)(BUF)*16384u + wave * 2048 + c * 1024), \
          16, 0, 0);                                                                          \
    }                                                                                         \
  }

  STAGE_E(0, 0);  // overlap subtile-0 DMA with A preload

  // ---- stage norms (fp32, already +2^35) into LDS; init keys ----
  nrmLds[t] = norms_g[t];
  nrmLds[t + 512] = norms_g[t + 512];
  if (t < BM) keys[t] = 0xFFFFFFFFu;

  // ---- A preload: 32 rows/wave (2 sets of 16), fp32 (nt) -> fp8 regs; ||x||^2 ----
  float xn = 0.f;
  long a[2][8];
#pragma unroll
  for (int s = 0; s < 2; ++s) {
    const f32x4* xr = (const f32x4*)(X + (rowBase + wr * 32 + s * 16 + lo16) * DD);
#pragma unroll
    for (int ks = 0; ks < 8; ++ks) {
      f32x4 v0 = __builtin_nontemporal_load(xr + ks * 8 + hi * 2);
      f32x4 v1 = __builtin_nontemporal_load(xr + ks * 8 + hi * 2 + 1);
#pragma unroll
      for (int j = 0; j < 4; ++j) xn = __builtin_fmaf(v0[j], v0[j], xn);
#pragma unroll
      for (int j = 0; j < 4; ++j) xn = __builtin_fmaf(v1[j], v1[j], xn);
      unsigned w0 = __builtin_amdgcn_cvt_pk_fp8_f32(v0[0], v0[1], 0, false);
      w0 = __builtin_amdgcn_cvt_pk_fp8_f32(v0[2], v0[3], w0, true);
      unsigned w1 = __builtin_amdgcn_cvt_pk_fp8_f32(v1[0], v1[1], 0, false);
      w1 = __builtin_amdgcn_cvt_pk_fp8_f32(v1[2], v1[3], w1, true);
      a[s][ks] = (long)w0 | ((long)w1 << 32);
    }
  }
  __syncthreads();  // nrmLds+keys visible; drains prologue vmem (STAGE(0) landed)

  unsigned best[2][4];
#pragma unroll
  for (int s = 0; s < 2; ++s)
#pragma unroll
    for (int r = 0; r < 4; ++r) best[s][r] = 0xFFFFFFFFu;

  const unsigned swzl = (unsigned)((lo16 & 7) << 4);
  unsigned nbase[2];
#pragma unroll
  for (int n = 0; n < 2; ++n) nbase[n] = (unsigned)((wc * 32 + n * 16 + lo16) * 256) ^ swzl;
  const unsigned hi64 = (unsigned)(hi * 64);

  for (int st = 0; st < NSUB; ++st) {
    // subtile top: issue next DMA, wait for this subtile's DMA, converge
    if (st + 1 < NSUB) {
      STAGE_E(st + 1, (st + 1) & 1);
      asm volatile("s_waitcnt vmcnt(2)" ::: "memory");  // stage(st) landed; st+1 in flight
    } else {
      asm volatile("s_waitcnt vmcnt(0)" ::: "memory");
    }
    __builtin_amdgcn_s_barrier();       // stage(st) visible to all waves
    __builtin_amdgcn_sched_barrier(0);

    const char* eb = ebBase + (st & 1) * 16384;
    f32x4 acc[2][2];
#pragma unroll
    for (int s = 0; s < 2; ++s)
#pragma unroll
      for (int n = 0; n < 2; ++n) {
        f32x4 z = {0.f, 0.f, 0.f, 0.f};
        acc[s][n] = z;
      }

    // ---- 4 phases: {issue 2 ds_read_b128 -> barrier -> lgkm(0) -> 8 MFMA} ----
#pragma unroll
    for (int kp = 0; kp < 4; ++kp) {
      const unsigned koff = hi64 + (unsigned)(kp * 16);  // bits 4-7; XOR vs swizzled base
      i64x2 b0 = *(const i64x2*)(eb + (nbase[0] ^ koff));
      i64x2 b1 = *(const i64x2*)(eb + (nbase[1] ^ koff));
      __builtin_amdgcn_sched_barrier(0);  // reads pinned before the barrier
      __builtin_amdgcn_s_barrier();       // phase gate: issue region / consume region
      asm volatile("s_waitcnt lgkmcnt(0)" ::: "memory");
      __builtin_amdgcn_sched_barrier(0);  // rule #18: MFMA must not hoist above wait
      __builtin_amdgcn_s_setprio(1);
      acc[0][0] = __builtin_amdgcn_mfma_f32_16x16x32_fp8_fp8(a[0][2 * kp], b0.x, acc[0][0], 0, 0, 0);
      acc[1][0] = __builtin_amdgcn_mfma_f32_16x16x32_fp8_fp8(a[1][2 * kp], b0.x, acc[1][0], 0, 0, 0);
      acc[0][1] = __builtin_amdgcn_mfma_f32_16x16x32_fp8_fp8(a[0][2 * kp], b1.x, acc[0][1], 0, 0, 0);
      acc[1][1] = __builtin_amdgcn_mfma_f32_16x16x32_fp8_fp8(a[1][2 * kp], b1.x, acc[1][1], 0, 0, 0);
      acc[0][0] = __builtin_amdgcn_mfma_f32_16x16x32_fp8_fp8(a[0][2 * kp + 1], b0.y, acc[0][0], 0, 0, 0);
      acc[1][0] = __builtin_amdgcn_mfma_f32_16x16x32_fp8_fp8(a[1][2 * kp + 1], b0.y, acc[1][0], 0, 0, 0);
      acc[0][1] = __builtin_amdgcn_mfma_f32_16x16x32_fp8_fp8(a[0][2 * kp + 1], b1.y, acc[0][1], 0, 0, 0);
      acc[1][1] = __builtin_amdgcn_mfma_f32_16x16x32_fp8_fp8(a[1][2 * kp + 1], b1.y, acc[1][1], 0, 0, 0);
      __builtin_amdgcn_s_setprio(0);
      __builtin_amdgcn_sched_barrier(0);
    }

    // ---- score region (register-only; scores positive -> no sign map) ----
#pragma unroll
    for (int n = 0; n < 2; ++n) {
      float nf = nrmLds[st * 64 + wc * 32 + n * 16 + lo16];
      unsigned code = (unsigned)(st * 64 + wc * 32 + n * 16 + lo16);
#pragma unroll
      for (int s = 0; s < 2; ++s)
#pragma unroll
        for (int r = 0; r < 4; ++r) {
          float sv = __builtin_fmaf(NEG2S, acc[s][n][r], nf);
          best[s][r] = umin2(best[s][r], (__float_as_uint(sv) & 0xFFFFFC00u) | code);
        }
    }
  }

  // ---- butterfly over the 16 code-lanes; merge code-halves via LDS atomicMin ----
#pragma unroll
  for (int s = 0; s < 2; ++s)
#pragma unroll
    for (int r = 0; r < 4; ++r) {
#pragma unroll
      for (int msk = 1; msk < 16; msk <<= 1)
        best[s][r] = umin2(best[s][r], (unsigned)__shfl_xor((int)best[s][r], msk));
    }
  if (lo16 == 0) {
#pragma unroll
    for (int s = 0; s < 2; ++s)
#pragma unroll
      for (int r = 0; r < 4; ++r) {
        // C/D layout: row_in_16 = hi*4 + r
        atomicMin(&keys[wr * 32 + s * 16 + hi * 4 + r], best[s][r]);
      }
  }

  // ---- wave-reduce ||x||^2 partials (count each row once: wc==0 only) ----
#pragma unroll
  for (int msk = 1; msk < 64; msk <<= 1) xn += __shfl_xor(xn, msk);
  if (lane == 0) wsumX[wave] = wc ? 0.0f : xn;

  __syncthreads();  // keys final; vmcnt fully drained (last iter waited vmcnt(0))

  float sc = 0.f;
  if (t < BM) {
    unsigned e = keys[t];
    // decode score (midpoint of truncated key), remove offset, rescale
    float sr = __uint_as_float((e & 0xFFFFFC00u) | 512u) - OFFS35;
    sc = sr * INV_S2;
  }
#pragma unroll
  for (int msk = 1; msk < 64; msk <<= 1) sc += __shfl_xor(sc, msk);
  if (lane == 0) wsumS[wave] = sc;

  // ---- gather fp32 codebook rows -> output (non-temporal store) ----
  {
    const f32x4* CBv = (const f32x4*)CB;
    f32x4* Og = (f32x4*)(out + rowBase * DD);
#pragma unroll 4
    for (int i = 0; i < 16; ++i) {
      int idx = t + NTHR * i;
      int row = idx >> 6, d4 = idx & 63;
      int code = (int)(keys[row] & 1023u);
      f32x4 e = CBv[code * 64 + d4];
      __builtin_nontemporal_store(e, Og + idx);
    }
  }

  __syncthreads();
  if (t == 0) {
    float tot = 0.f;
#pragma unroll
    for (int w = 0; w < 8; ++w) tot += wsumX[w] + wsumS[w];
    atomicAdd(loss_out, tot * lscale);
  }
}

extern "C" void kernel_launch(void* const* d_in, const int* in_sizes, int n_in,
                              void* d_out, int out_size, void* d_ws, size_t ws_size,
                              hipStream_t stream) {
  const float* X = (const float*)d_in[0];
  const float* CB = (const float*)d_in[1];
  float* out = (float*)d_out;

  const int ND = in_sizes[0];      // 16*4096*256 = 16777216
  const int K = in_sizes[1] / DD;  // 1024
  const int N = ND / DD;           // 65536

  float* ws_norms = (float*)d_ws;                               // K fp32 (4 KiB)
  unsigned char* ws_cb = (unsigned char*)((char*)d_ws + 4096);  // K*D fp8 (permuted)
  float* loss_out = out + (size_t)ND;

  vq_prep<<<K / 4, 256, 0, stream>>>(CB, ws_norms, ws_cb, loss_out);

  const float lscale = 1.25f / (float)ND;
  vq_main<<<N / BM, NTHR, 0, stream>>>(X, CB, ws_norms, ws_cb, out, loss_out, lscale);
}

// Round 17
// 53.498 us; speedup vs baseline: 1.1473x; 1.1473x over previous
//
#include <hip/hip_runtime.h>

typedef __attribute__((ext_vector_type(4))) float f32x4;
typedef __attribute__((ext_vector_type(2))) long i64x2;

#define SCALE 262144.0f                 // 2^18 codebook prescale
#define NEG2S -524288.0f                // -2 * SCALE
#define INV_S2 1.4551915228366852e-11f  // 2^-36, exact
#define OFFS35 34359738368.0f           // 2^35 positivity offset (scaled units)

static __device__ __forceinline__ unsigned umin2(unsigned a, unsigned b) { return a < b ? a : b; }

// exact e4m3fn decode (bias 7, 3-bit mantissa, denormals at 2^-9)
static __device__ __forceinline__ float dec_e4m3(unsigned b) {
  int e = (b >> 3) & 15, m = b & 7;
  float v = e ? ldexpf((float)(8 + m), e - 10) : ldexpf((float)m, -9);
  return (b & 0x80) ? -v : v;
}

// ---------------- Kernel 1: prep ----------------
// codebook fp32 -> (x SCALE) -> fp8 e4m3, PERMUTED: k = ks*32+hi*8+j stored at
// byte hi*64 + ks*8 + j (B-fragment order, ds_read_b128 covers 2 k-steps).
// norms[code] = 2^35 + sum(dec^2)  (offset makes all scores positive).
__global__ void vq_prep(const float* __restrict__ cb,
                        float* __restrict__ norms,
                        unsigned char* __restrict__ cbh,
                        float* __restrict__ loss_out) {
  if (blockIdx.x == 0 && threadIdx.x == 0) *loss_out = 0.0f;
  const int lane = threadIdx.x & 63;
  const int code = (blockIdx.x * blockDim.x + threadIdx.x) >> 6;  // one wave per code
  const f32x4 v = ((const f32x4*)(cb + (long)code * 256))[lane];  // k = 4*lane .. +3
  unsigned w = __builtin_amdgcn_cvt_pk_fp8_f32(v[0] * SCALE, v[1] * SCALE, 0, false);
  w = __builtin_amdgcn_cvt_pk_fp8_f32(v[2] * SCALE, v[3] * SCALE, w, true);
  float n = 0.f;
#pragma unroll
  for (int j = 0; j < 4; ++j) {
    float d = dec_e4m3((w >> (8 * j)) & 0xFFu);
    n = __builtin_fmaf(d, d, n);
  }
  // k0 = 4*lane: ks = lane>>3, hi = (lane>>1)&3, j0 = (lane&1)*4
  const int newpos = ((lane >> 1) & 3) * 64 + (lane >> 3) * 8 + (lane & 1) * 4;
  *(unsigned*)(cbh + (long)code * 256 + newpos) = w;
#pragma unroll
  for (int m = 1; m < 64; m <<= 1) n += __shfl_xor(n, m);
  if (lane == 0) norms[code] = n + OFFS35;
}

// ---------------- Kernel 2: main ----------------
// 8 waves = 4 row-groups (32 rows, M_w=32) x 2 code-halves (512 codes each).
// X staged once through LDS (fp8 fragment order) -> per-wave A regs.
#define BM 128    // rows per block
#define DD 256    // embedding dim
#define NTHR 512  // 8 waves
#define NSUB 16   // 1024 codes / 64 per subtile

__global__ __launch_bounds__(NTHR, 4)
void vq_main(const float* __restrict__ X,
             const float* __restrict__ CB,
             const float* __restrict__ norms_g,
             const unsigned char* __restrict__ cbh,
             float* __restrict__ out,
             float* __restrict__ loss_out,
             float lscale) {
  __shared__ __attribute__((aligned(16))) unsigned char Eb[2 * 16384];  // E dbuf 32 KiB
  __shared__ __attribute__((aligned(16))) unsigned char Xs[32768];      // X fp8 frags 32 KiB
  __shared__ __attribute__((aligned(16))) float nrmLds[1024];           // 4 KiB
  __shared__ unsigned keys[BM];
  __shared__ float wsumX[8];
  __shared__ float wsumS[8];

  const int t = threadIdx.x;
  const int lane = t & 63;
  const int wave = t >> 6;   // 0..7
  const int wr = wave >> 1;  // 0..3 : row-group (32 rows)
  const int wc = wave & 1;   // 0..1 : code half (32 codes of each 64-subtile)
  const int lo16 = lane & 15;
  const int hi = lane >> 4;
  const long rowBase = (long)blockIdx.x * BM;

  // ---- staging: subtile = 16 KiB; 8 waves x 2 chunks x (64 lanes x 16B).
  // LDS dest linear; global SOURCE pre-swizzled with involution o ^= ((o>>8)&7)<<4.
  const char* cbB = (const char*)cbh;
  char* ebBase = (char*)Eb;
#define STAGE_E(ST, BUF)                                                                      \
  {                                                                                           \
    _Pragma("unroll") for (int c = 0; c < 2; ++c) {                                           \
      unsigned o = (unsigned)(wave * 2048 + c * 1024 + lane * 16);                            \
      unsigned src = o ^ ((((o >> 8) & 7u)) << 4);                                            \
      __builtin_amdgcn_global_load_lds(                                                       \
          (const __attribute__((address_space(1))) void*)(cbB + (unsigned)(ST)*16384u + src), \
          (__attribute__((address_space(3))) void*)(ebBase + (unsigned)(BUF)*16384u + wave * 2048 + c * 1024), \
          16, 0, 0);                                                                          \
    }                                                                                         \
  }

  STAGE_E(0, 0);  // overlap subtile-0 DMA with X staging

  // ---- stage norms (fp32, already +2^35) into LDS; init keys ----
  nrmLds[t] = norms_g[t];
  nrmLds[t + 512] = norms_g[t + 512];
  if (t < BM) keys[t] = 0xFFFFFFFFu;

  // ---- X stage: wave stages rows wave*16..+15, fp32 (nt) -> fp8 frag order in Xs.
  // byte = row*256 + hi*64 + ks*8, swizzled ^(row&7)<<3.  Accumulate ||x||^2 once.
  float xn = 0.f;
  {
    const f32x4* xr = (const f32x4*)(X + (rowBase + wave * 16 + lo16) * DD);
    const unsigned row = (unsigned)(wave * 16 + lo16);
    const unsigned wbase = row * 256 + (unsigned)(hi * 64);
    const unsigned swz3 = (row & 7u) << 3;
#pragma unroll
    for (int ks = 0; ks < 8; ++ks) {
      f32x4 v0 = __builtin_nontemporal_load(xr + ks * 8 + hi * 2);
      f32x4 v1 = __builtin_nontemporal_load(xr + ks * 8 + hi * 2 + 1);
#pragma unroll
      for (int j = 0; j < 4; ++j) xn = __builtin_fmaf(v0[j], v0[j], xn);
#pragma unroll
      for (int j = 0; j < 4; ++j) xn = __builtin_fmaf(v1[j], v1[j], xn);
      unsigned w0 = __builtin_amdgcn_cvt_pk_fp8_f32(v0[0], v0[1], 0, false);
      w0 = __builtin_amdgcn_cvt_pk_fp8_f32(v0[2], v0[3], w0, true);
      unsigned w1 = __builtin_amdgcn_cvt_pk_fp8_f32(v1[0], v1[1], 0, false);
      w1 = __builtin_amdgcn_cvt_pk_fp8_f32(v1[2], v1[3], w1, true);
      *(long*)((char*)Xs + ((wbase + ks * 8) ^ swz3)) = (long)w0 | ((long)w1 << 32);
    }
  }
  __syncthreads();  // Xs + nrmLds + keys visible; prologue vmem drained (STAGE(0) landed)

  // ---- A-frag read: 32 rows/wave from Xs (one-time, 16 x ds_read_b64) ----
  long a[2][8];
#pragma unroll
  for (int s = 0; s < 2; ++s) {
    const unsigned row = (unsigned)(wr * 32 + s * 16 + lo16);
    const unsigned rbase = row * 256 + (unsigned)(hi * 64);
    const unsigned swz3 = (row & 7u) << 3;
#pragma unroll
    for (int ks = 0; ks < 8; ++ks)
      a[s][ks] = *(const long*)((const char*)Xs + ((rbase + ks * 8) ^ swz3));
  }

  unsigned best[2][4];
#pragma unroll
  for (int s = 0; s < 2; ++s)
#pragma unroll
    for (int r = 0; r < 4; ++r) best[s][r] = 0xFFFFFFFFu;

  const unsigned swzl = (unsigned)((lo16 & 7) << 4);
  unsigned nbase[2];
#pragma unroll
  for (int n = 0; n < 2; ++n) nbase[n] = (unsigned)((wc * 32 + n * 16 + lo16) * 256) ^ swzl;
  const unsigned hi64 = (unsigned)(hi * 64);

  for (int st = 0; st < NSUB; ++st) {
    // subtile top: issue next DMA, wait for this subtile's DMA, converge
    if (st + 1 < NSUB) {
      STAGE_E(st + 1, (st + 1) & 1);
      asm volatile("s_waitcnt vmcnt(2)" ::: "memory");  // stage(st) landed; st+1 in flight
    } else {
      asm volatile("s_waitcnt vmcnt(0)" ::: "memory");
    }
    __builtin_amdgcn_s_barrier();       // stage(st) visible to all waves
    __builtin_amdgcn_sched_barrier(0);

    const char* eb = ebBase + (st & 1) * 16384;
    f32x4 acc[2][2];
#pragma unroll
    for (int s = 0; s < 2; ++s)
#pragma unroll
      for (int n = 0; n < 2; ++n) {
        f32x4 z = {0.f, 0.f, 0.f, 0.f};
        acc[s][n] = z;
      }

    // ---- 2 phases: {issue 4 ds_read_b128 -> barrier -> lgkm(0) -> 16 MFMA} ----
#pragma unroll
    for (int ph = 0; ph < 2; ++ph) {
      const unsigned k0 = hi64 + (unsigned)(ph * 32);  // kp = 2ph (+16 -> kp = 2ph+1)
      i64x2 b0a = *(const i64x2*)(eb + (nbase[0] ^ k0));
      i64x2 b1a = *(const i64x2*)(eb + (nbase[1] ^ k0));
      i64x2 b0b = *(const i64x2*)(eb + (nbase[0] ^ (k0 + 16)));
      i64x2 b1b = *(const i64x2*)(eb + (nbase[1] ^ (k0 + 16)));
      __builtin_amdgcn_sched_barrier(0);  // reads pinned before the barrier
      __builtin_amdgcn_s_barrier();       // phase gate: issue region / consume region
      asm volatile("s_waitcnt lgkmcnt(0)" ::: "memory");
      __builtin_amdgcn_sched_barrier(0);  // rule #18: MFMA must not hoist above wait
      __builtin_amdgcn_s_setprio(1);
      const int kb = 4 * ph;
      acc[0][0] = __builtin_amdgcn_mfma_f32_16x16x32_fp8_fp8(a[0][kb], b0a.x, acc[0][0], 0, 0, 0);
      acc[1][0] = __builtin_amdgcn_mfma_f32_16x16x32_fp8_fp8(a[1][kb], b0a.x, acc[1][0], 0, 0, 0);
      acc[0][1] = __builtin_amdgcn_mfma_f32_16x16x32_fp8_fp8(a[0][kb], b1a.x, acc[0][1], 0, 0, 0);
      acc[1][1] = __builtin_amdgcn_mfma_f32_16x16x32_fp8_fp8(a[1][kb], b1a.x, acc[1][1], 0, 0, 0);
      acc[0][0] = __builtin_amdgcn_mfma_f32_16x16x32_fp8_fp8(a[0][kb + 1], b0a.y, acc[0][0], 0, 0, 0);
      acc[1][0] = __builtin_amdgcn_mfma_f32_16x16x32_fp8_fp8(a[1][kb + 1], b0a.y, acc[1][0], 0, 0, 0);
      acc[0][1] = __builtin_amdgcn_mfma_f32_16x16x32_fp8_fp8(a[0][kb + 1], b1a.y, acc[0][1], 0, 0, 0);
      acc[1][1] = __builtin_amdgcn_mfma_f32_16x16x32_fp8_fp8(a[1][kb + 1], b1a.y, acc[1][1], 0, 0, 0);
      acc[0][0] = __builtin_amdgcn_mfma_f32_16x16x32_fp8_fp8(a[0][kb + 2], b0b.x, acc[0][0], 0, 0, 0);
      acc[1][0] = __builtin_amdgcn_mfma_f32_16x16x32_fp8_fp8(a[1][kb + 2], b0b.x, acc[1][0], 0, 0, 0);
      acc[0][1] = __builtin_amdgcn_mfma_f32_16x16x32_fp8_fp8(a[0][kb + 2], b1b.x, acc[0][1], 0, 0, 0);
      acc[1][1] = __builtin_amdgcn_mfma_f32_16x16x32_fp8_fp8(a[1][kb + 2], b1b.x, acc[1][1], 0, 0, 0);
      acc[0][0] = __builtin_amdgcn_mfma_f32_16x16x32_fp8_fp8(a[0][kb + 3], b0b.y, acc[0][0], 0, 0, 0);
      acc[1][0] = __builtin_amdgcn_mfma_f32_16x16x32_fp8_fp8(a[1][kb + 3], b0b.y, acc[1][0], 0, 0, 0);
      acc[0][1] = __builtin_amdgcn_mfma_f32_16x16x32_fp8_fp8(a[0][kb + 3], b1b.y, acc[0][1], 0, 0, 0);
      acc[1][1] = __builtin_amdgcn_mfma_f32_16x16x32_fp8_fp8(a[1][kb + 3], b1b.y, acc[1][1], 0, 0, 0);
      __builtin_amdgcn_s_setprio(0);
      __builtin_amdgcn_sched_barrier(0);
    }

    // ---- score region (register-only; scores positive -> no sign map) ----
#pragma unroll
    for (int n = 0; n < 2; ++n) {
      float nf = nrmLds[st * 64 + wc * 32 + n * 16 + lo16];
      unsigned code = (unsigned)(st * 64 + wc * 32 + n * 16 + lo16);
#pragma unroll
      for (int s = 0; s < 2; ++s)
#pragma unroll
        for (int r = 0; r < 4; ++r) {
          float sv = __builtin_fmaf(NEG2S, acc[s][n][r], nf);
          best[s][r] = umin2(best[s][r], (__float_as_uint(sv) & 0xFFFFFC00u) | code);
        }
    }
  }

  // ---- butterfly over the 16 code-lanes; merge code-halves via LDS atomicMin ----
#pragma unroll
  for (int s = 0; s < 2; ++s)
#pragma unroll
    for (int r = 0; r < 4; ++r) {
#pragma unroll
      for (int msk = 1; msk < 16; msk <<= 1)
        best[s][r] = umin2(best[s][r], (unsigned)__shfl_xor((int)best[s][r], msk));
    }
  if (lo16 == 0) {
#pragma unroll
    for (int s = 0; s < 2; ++s)
#pragma unroll
      for (int r = 0; r < 4; ++r) {
        // C/D layout: row_in_16 = hi*4 + r
        atomicMin(&keys[wr * 32 + s * 16 + hi * 4 + r], best[s][r]);
      }
  }

  // ---- wave-reduce ||x||^2 partials (each row staged once -> counted once) ----
#pragma unroll
  for (int msk = 1; msk < 64; msk <<= 1) xn += __shfl_xor(xn, msk);
  if (lane == 0) wsumX[wave] = xn;

  __syncthreads();  // keys final; vmcnt fully drained (last iter waited vmcnt(0))

  float sc = 0.f;
  if (t < BM) {
    unsigned e = keys[t];
    // decode score (midpoint of truncated key), remove offset, rescale
    float sr = __uint_as_float((e & 0xFFFFFC00u) | 512u) - OFFS35;
    sc = sr * INV_S2;
  }
#pragma unroll
  for (int msk = 1; msk < 64; msk <<= 1) sc += __shfl_xor(sc, msk);
  if (lane == 0) wsumS[wave] = sc;

  // ---- gather fp32 codebook rows -> output (non-temporal store) ----
  {
    const f32x4* CBv = (const f32x4*)CB;
    f32x4* Og = (f32x4*)(out + rowBase * DD);
#pragma unroll 4
    for (int i = 0; i < 16; ++i) {
      int idx = t + NTHR * i;
      int row = idx >> 6, d4 = idx & 63;
      int code = (int)(keys[row] & 1023u);
      f32x4 e = CBv[code * 64 + d4];
      __builtin_nontemporal_store(e, Og + idx);
    }
  }

  __syncthreads();
  if (t == 0) {
    float tot = 0.f;
#pragma unroll
    for (int w = 0; w < 8; ++w) tot += wsumX[w] + wsumS[w];
    atomicAdd(loss_out, tot * lscale);
  }
}

extern "C" void kernel_launch(void* const* d_in, const int* in_sizes, int n_in,
                              void* d_out, int out_size, void* d_ws, size_t ws_size,
                              hipStream_t stream) {
  const float* X = (const float*)d_in[0];
  const float* CB = (const float*)d_in[1];
  float* out = (float*)d_out;

  const int ND = in_sizes[0];      // 16*4096*256 = 16777216
  const int K = in_sizes[1] / DD;  // 1024
  const int N = ND / DD;           // 65536

  float* ws_norms = (float*)d_ws;                               // K fp32 (4 KiB)
  unsigned char* ws_cb = (unsigned char*)((char*)d_ws + 4096);  // K*D fp8 (permuted)
  float* loss_out = out + (size_t)ND;

  vq_prep<<<K / 4, 256, 0, stream>>>(CB, ws_norms, ws_cb, loss_out);

  const float lscale = 1.25f / (float)ND;
  vq_main<<<N / BM, NTHR, 0, stream>>>(X, CB, ws_norms, ws_cb, out, loss_out, lscale);
}